// Round 18
// baseline (80.306 us; speedup 1.0000x reference)
//
#include <hip/hip_runtime.h>

#define BS 4096
#define LL 512
#define NB 8                  // batches per block (MFMA cols 8..15 duplicate 0..7)
#define NCH 32                // chunks of 16 steps
#define HT 256                // timesteps staged per half
#define SCWD 65               // dwords per staged t-row (8b*16r bf16 = 64 + 1 pad)
#define SCW 130               // ushorts per t-row
#define START_TAG 1
#define END_TAG 2
#define BIASF 4.5f            // per-applied-step 2^-BIASF (restored exactly in log2)
#define L2E 1.44269504f
#define LN2 0.69314718055994531f

typedef float f32x4 __attribute__((ext_vector_type(4)));
typedef short s16x4 __attribute__((ext_vector_type(4)));
union BF4 { unsigned u[2]; s16x4 s; };

__device__ __forceinline__ unsigned cvt_pk_bf16(float lo, float hi) {
    unsigned r;
    asm("v_cvt_pk_bf16_f32 %0, %1, %2" : "=v"(r) : "v"(lo), "v"(hi));
    return r;
}
__device__ __forceinline__ float blo(unsigned u) { return __uint_as_float(u << 16); }
__device__ __forceinline__ float bhi(unsigned u) { return __uint_as_float(u & 0xFFFF0000u); }
__device__ __forceinline__ float b2f(unsigned short h) { return __uint_as_float(((unsigned)h) << 16); }

#define CSTEP(SV, P01, P23) { \
        const float f0 = blo((SV).x), f1 = bhi((SV).x); \
        const float f2 = blo((SV).y), f3 = bhi((SV).y); \
        BF4 Bf; Bf.u[0] = P01; Bf.u[1] = P23; \
        f32x4 z = {0.f, 0.f, 0.f, 0.f}; \
        f32x4 d = __builtin_amdgcn_mfma_f32_16x16x16bf16_1k(Af.s, Bf.s, z, 0, 0, 0); \
        P01 = cvt_pk_bf16(d[0] * f0, d[1] * f1); \
        P23 = cvt_pk_bf16(d[2] * f2, d[3] * f3); }

#define CSTEPM(SV, MB, S, P01, P23) { \
        const float f0 = blo((SV).x), f1 = bhi((SV).x); \
        const float f2 = blo((SV).y), f3 = bhi((SV).y); \
        BF4 Bf; Bf.u[0] = P01; Bf.u[1] = P23; \
        f32x4 z = {0.f, 0.f, 0.f, 0.f}; \
        f32x4 d = __builtin_amdgcn_mfma_f32_16x16x16bf16_1k(Af.s, Bf.s, z, 0, 0, 0); \
        const unsigned n01 = cvt_pk_bf16(d[0] * f0, d[1] * f1); \
        const unsigned n23 = cvt_pk_bf16(d[2] * f2, d[3] * f3); \
        const bool up = (((MB) >> (S)) & 1u) != 0u; \
        P01 = up ? n01 : P01; \
        P23 = up ? n23 : P23; }

#define RENORM(P01, P23, E2F) { \
        const float v0 = blo(P01), v1 = bhi(P01), v2 = blo(P23), v3 = bhi(P23); \
        float mm = fmaxf(fmaxf(v0, v1), fmaxf(v2, v3)); \
        mm = fmaxf(mm, __shfl_xor(mm, 16)); \
        mm = fmaxf(mm, __shfl_xor(mm, 32)); \
        if (mm > 0.f) { \
            const int ex = (int)((__float_as_uint(mm) >> 23) & 0xFFu) - 127; \
            const float sre = __uint_as_float((unsigned)(127 - ex) << 23); \
            E2F += (float)ex; \
            P01 = cvt_pk_bf16(v0 * sre, v1 * sre); \
            P23 = cvt_pk_bf16(v2 * sre, v3 * sre); } }

// Two independent 16-step chunks advanced alternately (2x chain ILP),
// each with 1-step-ahead rolling LDS prefetch. Validated r17 step math.
__device__ __forceinline__ void chain16_dual(
    const unsigned* __restrict__ sSC, int ta, int tb, int jq_off, const BF4& Af,
    unsigned mba, unsigned mbb,
    unsigned& a01, unsigned& a23, unsigned& b01, unsigned& b23,
    float& ea, float& eb)
{
    const int basea = ta * SCWD + jq_off;
    const int baseb = tb * SCWD + jq_off;
    uint2 svA = *(const uint2*)(sSC + basea);
    uint2 svB = *(const uint2*)(sSC + baseb);
    if (__all((mba == 0xFFFFu) & (mbb == 0xFFFFu))) {
#pragma unroll
        for (int s = 0; s < 16; ++s) {
            const uint2 nA = (s < 15) ? *(const uint2*)(sSC + basea + (s + 1) * SCWD) : svA;
            const uint2 nB = (s < 15) ? *(const uint2*)(sSC + baseb + (s + 1) * SCWD) : svB;
            CSTEP(svA, a01, a23)
            CSTEP(svB, b01, b23)
            svA = nA; svB = nB;
        }
    } else {
#pragma unroll
        for (int s = 0; s < 16; ++s) {
            const uint2 nA = (s < 15) ? *(const uint2*)(sSC + basea + (s + 1) * SCWD) : svA;
            const uint2 nB = (s < 15) ? *(const uint2*)(sSC + baseb + (s + 1) * SCWD) : svB;
            CSTEPM(svA, mba, s, a01, a23)
            CSTEPM(svB, mbb, s, b01, b23)
            svA = nA; svB = nB;
        }
    }
    RENORM(a01, a23, ea)
    RENORM(b01, b23, eb)
}

// Fused CRF: block = 8 batches, 8 waves, 2 blocks/CU. Two staged halves; per
// half: stage bf16 exp-scales -> LDS, score from staged scales, pass1 (chunks
// from ones, dual), pass2 (from y_{c-1}, dual). Telescoped rank-1 combine.
__global__ __launch_bounds__(512) void crf_p2(
    const float* __restrict__ em, const int* __restrict__ tg,
    const float* __restrict__ mk, const float* __restrict__ tr,
    float* __restrict__ out)
{
    __shared__ unsigned sSC[HT * SCWD];            // 66560 B bf16 scales
    __shared__ unsigned sYp[NCH * NB * 8];         // 8 KB packed bf16 y-vectors
    __shared__ float sYs[NCH][NB], sRs[NCH][NB], sF[NCH][NB], sG[NCH][NB];
    __shared__ unsigned short sMB[NCH][NB];        // per-(chunk,batch) mask bits
    __shared__ float sTR[256];
    __shared__ float sSc[NB], sRes[NB];

    const int tid = threadIdx.x;
    const int wv = tid >> 6, lane = tid & 63;
    const int j = lane & 15, q = lane >> 4;
    const int jj = j & 7;                          // batch (cols 8..15 duplicate)
    const long gb0 = (long)blockIdx.x * NB;

    if (tid < 64) *(f32x4*)(sTR + tid * 4) = *(const f32x4*)(tr + tid * 4);

    int is64 = 1;
    {
        const unsigned long long* t64 = (const unsigned long long*)tg;
#pragma unroll
        for (int i = 0; i < 16; ++i) is64 &= (t64[i] < 16ull) ? 1 : 0;
    }
    const int esz = is64 ? 2 : 1;

    // mask bitmask: wave wv = batch wv
    {
        const float* mp = mk + (gb0 + wv) * (long)LL;
#pragma unroll
        for (int k = 0; k < 8; ++k) {
            const unsigned long long bal = __ballot(mp[k * 64 + lane] > 0.f);
            if (lane == 0) {
                sMB[4 * k + 0][wv] = (unsigned short)(bal);
                sMB[4 * k + 1][wv] = (unsigned short)(bal >> 16);
                sMB[4 * k + 2][wv] = (unsigned short)(bal >> 32);
                sMB[4 * k + 3][wv] = (unsigned short)(bal >> 48);
            }
        }
    }
    __syncthreads();

    // static A = E^T: lane (j,q) holds A[j][4q+i] = exp(tr[4q+i][j])  (validated)
    BF4 Af;
    {
        float Ef[4];
#pragma unroll
        for (int i = 0; i < 4; ++i)
            Ef[i] = exp2f(sTR[(q * 4 + i) * 16 + j] * L2E);   // exp(-1000) -> 0
        Af.u[0] = cvt_pk_bf16(Ef[0], Ef[1]);
        Af.u[1] = cvt_pk_bf16(Ef[2], Ef[3]);
    }
    const int jq_off = jj * 8 + 2 * q;

    float scoreAcc = 0.f;

    for (int h = 0; h < 2; ++h) {
        // ---- stage half h: coalesced em -> exp2 -> bf16 LDS [t][b][r] ----
#pragma unroll 4
        for (int it = 0; it < 16; ++it) {
            const int flat = tid * 4 + it * 2048;   // [b:3][t:8][r:4]
            const int bl = flat >> 12, t = (flat >> 4) & 255, r4 = flat & 15;
            const f32x4 v = *(const f32x4*)(em + ((gb0 + bl) * (long)LL + h * HT + t) * 16 + r4);
            const float e0 = exp2f(fmaf(v.x, L2E, -BIASF));
            const float e1 = exp2f(fmaf(v.y, L2E, -BIASF));
            const float e2 = exp2f(fmaf(v.z, L2E, -BIASF));
            const float e3 = exp2f(fmaf(v.w, L2E, -BIASF));
            uint2 w; w.x = cvt_pk_bf16(e0, e1); w.y = cvt_pk_bf16(e2, e3);
            *(uint2*)(sSC + t * SCWD + bl * 8 + (r4 >> 1)) = w;
        }
        __syncthreads();

        // ---- score half h (wave wv = batch wv), em reconstructed from scales ----
        {
            const long bb = (gb0 + wv) * (long)LL;
            const unsigned short* sc16 = (const unsigned short*)sSC;
#pragma unroll
            for (int k = 0; k < 4; ++k) {
                const int tl = k * 64 + lane;
                const int t = h * HT + tl;
                const int tcur = tg[(bb + t) * esz];
                const long pidx = (bb + (t == 0 ? 1 : t) - 1) * esz;   // in-bounds
                const int tpv = (t == 0) ? START_TAG : tg[pidx];
                const float mbit = (float)((sMB[t >> 4][wv] >> (t & 15)) & 1);
                const float scm = (t == 0) ? 1.f : mbit;
                const float sc = b2f(sc16[tl * SCW + wv * 16 + tcur]);
                const float emr = (log2f(fmaxf(sc, 1e-37f)) + BIASF) * LN2;
                scoreAcc = fmaf(emr + sTR[tpv * 16 + tcur], scm, scoreAcc);
            }
        }

        // ---- pass1: chunks c1 = h*16+wv, c2 = h*16+8+wv, from ones (dual) ----
        const int c1 = h * 16 + wv, c2 = c1 + 8;
        const unsigned mb1 = (unsigned)sMB[c1][jj];
        const unsigned mb2 = (unsigned)sMB[c2][jj];
        {
            unsigned a01 = 0x3F803F80u, a23 = 0x3F803F80u;
            unsigned b01 = 0x3F803F80u, b23 = 0x3F803F80u;
            float ea = 0.f, eb = 0.f;
            chain16_dual(sSC, wv * 16, (wv + 8) * 16, jq_off, Af,
                         mb1, mb2, a01, a23, b01, b23, ea, eb);
            uint2 ya; ya.x = a01; ya.y = a23;
            uint2 yb; yb.x = b01; yb.y = b23;
            *(uint2*)(sYp + (c1 * NB + jj) * 8 + 2 * q) = ya;
            *(uint2*)(sYp + (c2 * NB + jj) * 8 + 2 * q) = yb;
            float sa = blo(a01) + bhi(a01) + blo(a23) + bhi(a23);
            float sb = blo(b01) + bhi(b01) + blo(b23) + bhi(b23);
            sa += __shfl_xor(sa, 16); sa += __shfl_xor(sa, 32);
            sb += __shfl_xor(sb, 16); sb += __shfl_xor(sb, 32);
            if (lane < 8) {
                sYs[c1][jj] = sa; sF[c1][jj] = ea + BIASF * (float)__popc(mb1);
                sYs[c2][jj] = sb; sF[c2][jj] = eb + BIASF * (float)__popc(mb2);
            }
        }
        __syncthreads();

        // ---- pass2: same chunks from y_{c-1} (c1==0 computed then discarded) ----
        {
            const int p1 = (c1 > 0) ? (c1 - 1) : 0;
            const uint2 y1 = *(const uint2*)(sYp + (p1 * NB + jj) * 8 + 2 * q);
            const uint2 y2 = *(const uint2*)(sYp + ((c2 - 1) * NB + jj) * 8 + 2 * q);
            unsigned a01 = y1.x, a23 = y1.y, b01 = y2.x, b23 = y2.y;
            float ea = 0.f, eb = 0.f;
            chain16_dual(sSC, wv * 16, (wv + 8) * 16, jq_off, Af,
                         mb1, mb2, a01, a23, b01, b23, ea, eb);
            float sa = blo(a01) + bhi(a01) + blo(a23) + bhi(a23);
            float sb = blo(b01) + bhi(b01) + blo(b23) + bhi(b23);
            sa += __shfl_xor(sa, 16); sa += __shfl_xor(sa, 32);
            sb += __shfl_xor(sb, 16); sb += __shfl_xor(sb, 32);
            if (lane < 8) {
                sRs[c1][jj] = sa; sG[c1][jj] = ea + BIASF * (float)__popc(mb1);
                sRs[c2][jj] = sb; sG[c2][jj] = eb + BIASF * (float)__popc(mb2);
            }
        }
        __syncthreads();
    }

    // ---- score reduce ----
#pragma unroll
    for (int o = 1; o <= 32; o <<= 1) scoreAcc += __shfl_xor(scoreAcc, o);
    if (lane == 0) sSc[wv] = scoreAcc;
    __syncthreads();

    // ---- combine: 128 threads = 8 batches x 16 rows ----
    if (tid < 128) {
        const int b = tid >> 4, row = tid & 15;
        const unsigned short* yp16 = (const unsigned short*)sYp;
        float x = b2f(yp16[((NCH - 1) * NB + b) * 16 + row])
                * exp2f(sTR[row * 16 + END_TAG] * L2E);
#pragma unroll
        for (int o = 1; o <= 8; o <<= 1) x += __shfl_xor(x, o, 16);
        if (row == 0) {
            float l2 = log2f(fmaxf(x, 1e-37f)) + sF[0][b];
#pragma unroll
            for (int c = 1; c < NCH; ++c)
                l2 += log2f(fmaxf(sRs[c][b], 1e-37f))
                    - log2f(fmaxf(sYs[c][b], 1e-37f)) + sG[c][b];
            int cnt = 0;
#pragma unroll
            for (int c = 0; c < NCH; ++c) cnt += __popc((unsigned)sMB[c][b]);
            const int li = (cnt > 0) ? (cnt - 1) : 0;
            const int lt = tg[((gb0 + b) * (long)LL + li) * esz];
            sRes[b] = LN2 * l2 - (sSc[b] + sTR[lt * 16 + END_TAG]);
        }
    }
    __syncthreads();
    if (tid == 0) {
        float s = 0.f;
#pragma unroll
        for (int i = 0; i < NB; ++i) s += sRes[i];
        atomicAdd(out, s);
    }
}

extern "C" void kernel_launch(void* const* d_in, const int* in_sizes, int n_in,
                              void* d_out, int out_size, void* d_ws, size_t ws_size,
                              hipStream_t stream) {
    const float* em = (const float*)d_in[0];
    const int*   tg = (const int*)d_in[1];
    const float* mk = (const float*)d_in[2];
    const float* tr = (const float*)d_in[3];
    float* out = (float*)d_out;

    hipMemsetAsync(out, 0, sizeof(float), stream);
    crf_p2<<<BS / NB, 512, 0, stream>>>(em, tg, mk, tr, out);
}

// Round 20
// 65.748 us; speedup vs baseline: 1.2214x; 1.2214x over previous
//
#include <hip/hip_runtime.h>

#define BS 4096
#define LL 512
#define NB 16                 // batches per block = MFMA columns
#define NCH 16                // chunks of 32 steps
#define QR 128                // staged rows (steps) per quarter
#define SCWD 130              // dwords per staged t-row (16b * 4 quads * 2 + pad)
#define START_TAG 1
#define END_TAG 2
#define BIASF 4.5f            // per-applied-step 2^-BIASF (restored exactly in log2)
#define L2E 1.44269504f
#define LN2 0.69314718055994531f

typedef float f32x4 __attribute__((ext_vector_type(4)));
typedef short s16x4 __attribute__((ext_vector_type(4)));
union BF4 { unsigned u[2]; s16x4 s; };

__device__ __forceinline__ unsigned cvt_pk_bf16(float lo, float hi) {
    unsigned r;
    asm("v_cvt_pk_bf16_f32 %0, %1, %2" : "=v"(r) : "v"(lo), "v"(hi));
    return r;
}
__device__ __forceinline__ float blo(unsigned u) { return __uint_as_float(u << 16); }
__device__ __forceinline__ float bhi(unsigned u) { return __uint_as_float(u & 0xFFFF0000u); }

#define CSTEP(SV, P01, P23) { \
        const float f0 = blo((SV).x), f1 = bhi((SV).x); \
        const float f2 = blo((SV).y), f3 = bhi((SV).y); \
        BF4 Bf; Bf.u[0] = P01; Bf.u[1] = P23; \
        f32x4 z = {0.f, 0.f, 0.f, 0.f}; \
        f32x4 d = __builtin_amdgcn_mfma_f32_16x16x16bf16_1k(Af.s, Bf.s, z, 0, 0, 0); \
        P01 = cvt_pk_bf16(d[0] * f0, d[1] * f1); \
        P23 = cvt_pk_bf16(d[2] * f2, d[3] * f3); }

#define CSTEPM(SV, MB, S, P01, P23) { \
        const float f0 = blo((SV).x), f1 = bhi((SV).x); \
        const float f2 = blo((SV).y), f3 = bhi((SV).y); \
        BF4 Bf; Bf.u[0] = P01; Bf.u[1] = P23; \
        f32x4 z = {0.f, 0.f, 0.f, 0.f}; \
        f32x4 d = __builtin_amdgcn_mfma_f32_16x16x16bf16_1k(Af.s, Bf.s, z, 0, 0, 0); \
        const unsigned n01 = cvt_pk_bf16(d[0] * f0, d[1] * f1); \
        const unsigned n23 = cvt_pk_bf16(d[2] * f2, d[3] * f3); \
        const bool up = (((MB) >> (S)) & 1u) != 0u; \
        P01 = up ? n01 : P01; \
        P23 = up ? n23 : P23; }

#define RENORM(P01, P23, E2F) { \
        const float v0 = blo(P01), v1 = bhi(P01), v2 = blo(P23), v3 = bhi(P23); \
        float mm = fmaxf(fmaxf(v0, v1), fmaxf(v2, v3)); \
        mm = fmaxf(mm, __shfl_xor(mm, 16)); \
        mm = fmaxf(mm, __shfl_xor(mm, 32)); \
        if (mm > 0.f) { \
            const int ex = (int)((__float_as_uint(mm) >> 23) & 0xFFu) - 127; \
            const float sre = __uint_as_float((unsigned)(127 - ex) << 23); \
            E2F += (float)ex; \
            P01 = cvt_pk_bf16(v0 * sre, v1 * sre); \
            P23 = cvt_pk_bf16(v2 * sre, v3 * sre); } }

#define STAGE_DECODE(QID, BL, TROW, C4) \
        const int BL = (QID) >> 9; \
        const int TROW = ((QID) & 511) >> 2; \
        const int C4 = (QID) & 3;

#define STAGE_WRITE(SLOT, QID, V) { \
        STAGE_DECODE(QID, bl_, trow_, c4_) \
        const float e0 = exp2f(fmaf((V).x, L2E, -BIASF)); \
        const float e1 = exp2f(fmaf((V).y, L2E, -BIASF)); \
        const float e2 = exp2f(fmaf((V).z, L2E, -BIASF)); \
        const float e3 = exp2f(fmaf((V).w, L2E, -BIASF)); \
        uint2 w_; w_.x = cvt_pk_bf16(e0, e1); w_.y = cvt_pk_bf16(e2, e3); \
        *(uint2*)(sSC + (SLOT) * (QR * SCWD) + trow_ * SCWD + bl_ * 8 + 2 * c4_) = w_; }

// Pipelined CRF: block = 16 batches, 16 waves. 2 LDS quarter-slots.
// Iter k: waves 4k..4k+3 chain chunks 4k..4k+3 on slot[k&1] (pass1 then pass2,
// r17-validated math) while the other 12 waves stage quarter k+1 into the
// other slot. Score reads raw em afterwards (L3-hot). Telescoped combine.
__global__ __launch_bounds__(1024) void crf_pipe(
    const float* __restrict__ em, const int* __restrict__ tg,
    const float* __restrict__ mk, const float* __restrict__ tr,
    float* __restrict__ out)
{
    __shared__ unsigned sSC[2 * QR * SCWD];        // 133120 B staged bf16 scales
    __shared__ unsigned sYp[NCH * NB * 8];         // 8 KB packed bf16 y-vectors
    __shared__ float sYs[NCH][NB], sRs[NCH][NB], sF[NCH][NB], sG[NCH][NB];
    __shared__ unsigned sMB[NCH][NB];              // 32-bit per-(chunk,batch) masks
    __shared__ float sTR[256];
    __shared__ float sSc[NB], sRes[NB];

    const int tid = threadIdx.x;
    const int wv = tid >> 6, lane = tid & 63;
    const int j = lane & 15, q = lane >> 4;
    const long gb0 = (long)blockIdx.x * NB;

    if (tid < 64) *(f32x4*)(sTR + tid * 4) = *(const f32x4*)(tr + tid * 4);

    int is64 = 1;
    {
        const unsigned long long* t64 = (const unsigned long long*)tg;
#pragma unroll
        for (int i = 0; i < 16; ++i) is64 &= (t64[i] < 16ull) ? 1 : 0;
    }
    const int esz = is64 ? 2 : 1;

    // mask bits: wave wv = batch wv; chunk c = t>>5, bit = t&31
    {
        const float* mp = mk + (gb0 + wv) * (long)LL;
#pragma unroll
        for (int k = 0; k < 8; ++k) {
            const unsigned long long bal = __ballot(mp[k * 64 + lane] > 0.f);
            if (lane == 0) {
                sMB[2 * k + 0][wv] = (unsigned)bal;
                sMB[2 * k + 1][wv] = (unsigned)(bal >> 32);
            }
        }
    }
    __syncthreads();

    // static A = E^T (validated): lane (j,q) holds A[j][4q+i] = exp(tr[4q+i][j])
    BF4 Af;
    {
        float Ef[4];
#pragma unroll
        for (int i = 0; i < 4; ++i)
            Ef[i] = exp2f(sTR[(q * 4 + i) * 16 + j] * L2E);   // exp(-1000) -> 0
        Af.u[0] = cvt_pk_bf16(Ef[0], Ef[1]);
        Af.u[1] = cvt_pk_bf16(Ef[2], Ef[3]);
    }
    const int jqoff = j * 8 + 2 * q;

    // ---- prestage quarter 0 -> slot 0 (all 16 waves; 8 iters, loads batched) --
    {
        f32x4 vv[8];
#pragma unroll
        for (int it = 0; it < 8; ++it) {
            const int qid = tid + it * 1024;
            STAGE_DECODE(qid, bl, trow, c4)
            vv[it] = *(const f32x4*)(em + ((gb0 + bl) * (long)LL + trow) * 16 + 4 * c4);
        }
#pragma unroll
        for (int it = 0; it < 8; ++it) STAGE_WRITE(0, tid + it * 1024, vv[it])
    }
    __syncthreads();

    // ---- main pipeline ----
    for (int k = 0; k < 4; ++k) {
        const int slot = k & 1;
        const bool chainw = ((wv >> 2) == k);      // wave-uniform
        const int c = wv;                          // chunk id when chainw
        const int sidx = (wv < 4 * k) ? wv : wv - 4;
        const unsigned mbc = sMB[wv & 15][j];      // chain waves: their chunk's mask

        unsigned p01 = 0x3F803F80u, p23 = 0x3F803F80u;
        float e2f = 0.f;

        // phase A: pass1 || stage part A (6 iters)
        if (chainw) {
            const int base = slot * (QR * SCWD) + ((c & 3) * 32) * SCWD + jqoff;
            uint2 sv = *(const uint2*)(sSC + base);
            if (__all(mbc == 0xFFFFFFFFu)) {
#pragma unroll
                for (int s = 0; s < 32; ++s) {
                    const uint2 nx = (s < 31) ? *(const uint2*)(sSC + base + (s + 1) * SCWD) : sv;
                    CSTEP(sv, p01, p23)
                    sv = nx;
                    if (s == 15) RENORM(p01, p23, e2f)
                }
            } else {
#pragma unroll
                for (int s = 0; s < 32; ++s) {
                    const uint2 nx = (s < 31) ? *(const uint2*)(sSC + base + (s + 1) * SCWD) : sv;
                    CSTEPM(sv, mbc, s, p01, p23)
                    sv = nx;
                    if (s == 15) RENORM(p01, p23, e2f)
                }
            }
            RENORM(p01, p23, e2f)
            uint2 y; y.x = p01; y.y = p23;
            *(uint2*)(sYp + (c * 16 + j) * 8 + 2 * q) = y;
            float sa = blo(p01) + bhi(p01) + blo(p23) + bhi(p23);
            sa += __shfl_xor(sa, 16);
            sa += __shfl_xor(sa, 32);
            if (lane < 16) {
                sYs[c][j] = sa;
                sF[c][j] = e2f + BIASF * (float)__popc(mbc);
            }
        } else if (k < 3) {
            f32x4 vv[6];
#pragma unroll
            for (int it = 0; it < 6; ++it) {
                const int qid = sidx * 64 + lane + it * 768;
                STAGE_DECODE(qid, bl, trow, c4)
                vv[it] = *(const f32x4*)(em + ((gb0 + bl) * (long)LL + (k + 1) * QR + trow) * 16 + 4 * c4);
            }
#pragma unroll
            for (int it = 0; it < 6; ++it) STAGE_WRITE(slot ^ 1, sidx * 64 + lane + it * 768, vv[it])
        }
        __syncthreads();

        // phase B: pass2 || stage part B (5 iters, guarded)
        if (chainw) {
            if (c > 0) {
                const uint2 y = *(const uint2*)(sYp + ((c - 1) * 16 + j) * 8 + 2 * q);
                unsigned r01 = y.x, r23 = y.y;
                float g2f = 0.f;
                const int base = slot * (QR * SCWD) + ((c & 3) * 32) * SCWD + jqoff;
                uint2 sv = *(const uint2*)(sSC + base);
                if (__all(mbc == 0xFFFFFFFFu)) {
#pragma unroll
                    for (int s = 0; s < 32; ++s) {
                        const uint2 nx = (s < 31) ? *(const uint2*)(sSC + base + (s + 1) * SCWD) : sv;
                        CSTEP(sv, r01, r23)
                        sv = nx;
                        if (s == 15) RENORM(r01, r23, g2f)
                    }
                } else {
#pragma unroll
                    for (int s = 0; s < 32; ++s) {
                        const uint2 nx = (s < 31) ? *(const uint2*)(sSC + base + (s + 1) * SCWD) : sv;
                        CSTEPM(sv, mbc, s, r01, r23)
                        sv = nx;
                        if (s == 15) RENORM(r01, r23, g2f)
                    }
                }
                RENORM(r01, r23, g2f)
                float sb = blo(r01) + bhi(r01) + blo(r23) + bhi(r23);
                sb += __shfl_xor(sb, 16);
                sb += __shfl_xor(sb, 32);
                if (lane < 16) {
                    sRs[c][j] = sb;
                    sG[c][j] = g2f + BIASF * (float)__popc(mbc);
                }
            }
        } else if (k < 3) {
            f32x4 vv[5];
#pragma unroll
            for (int it = 0; it < 5; ++it) {
                const int qid = sidx * 64 + lane + (6 + it) * 768;
                const int qc = (qid < 8192) ? qid : 8191;
                STAGE_DECODE(qc, bl, trow, c4)
                vv[it] = *(const f32x4*)(em + ((gb0 + bl) * (long)LL + (k + 1) * QR + trow) * 16 + 4 * c4);
            }
#pragma unroll
            for (int it = 0; it < 5; ++it) {
                const int qid = sidx * 64 + lane + (6 + it) * 768;
                if (qid < 8192) STAGE_WRITE(slot ^ 1, qid, vv[it])
            }
        }
        __syncthreads();
    }

    // ---- score: wave wv = batch wv, raw em (exact fp32, L3-hot) ----
    float scoreAcc = 0.f;
    {
        const long bb = (gb0 + wv) * (long)LL;
#pragma unroll
        for (int k2 = 0; k2 < 8; ++k2) {
            const int t = k2 * 64 + lane;
            const int tcur = tg[(bb + t) * esz];
            const long pidx = (bb + (t == 0 ? 1 : t) - 1) * esz;
            const int tpv = (t == 0) ? START_TAG : (int)tg[pidx];
            const float mbit = (float)((sMB[t >> 5][wv] >> (t & 31)) & 1u);
            const float scm = (t == 0) ? 1.f : mbit;
            scoreAcc = fmaf(em[(bb + t) * 16 + tcur] + sTR[tpv * 16 + tcur], scm, scoreAcc);
        }
#pragma unroll
        for (int o = 1; o <= 32; o <<= 1) scoreAcc += __shfl_xor(scoreAcc, o);
        if (lane == 0) sSc[wv] = scoreAcc;
    }
    __syncthreads();

    // ---- combine (r17-validated telescope): 256 threads = 16 b x 16 rows ----
    if (tid < 256) {
        const int b = tid >> 4, row = tid & 15;
        const unsigned short* yp16 = (const unsigned short*)sYp;
        float x = __uint_as_float(((unsigned)yp16[((NCH - 1) * 16 + b) * 16 + row]) << 16)
                * exp2f(sTR[row * 16 + END_TAG] * L2E);
#pragma unroll
        for (int o = 1; o <= 8; o <<= 1) x += __shfl_xor(x, o, 16);
        if (row == 0) {
            float l2 = log2f(fmaxf(x, 1e-37f)) + sF[NCH - 1][b];
#pragma unroll
            for (int c2 = 1; c2 < NCH; ++c2)
                l2 += log2f(fmaxf(sRs[c2][b], 1e-37f))
                    - log2f(fmaxf(sYs[c2][b], 1e-37f))
                    + sG[c2][b] + sF[c2 - 1][b] - sF[c2][b];
            int cnt = 0;
#pragma unroll
            for (int c2 = 0; c2 < NCH; ++c2) cnt += __popc(sMB[c2][b]);
            const int li = (cnt > 0) ? (cnt - 1) : 0;
            const int lt = tg[((gb0 + b) * (long)LL + li) * esz];
            sRes[b] = LN2 * l2 - (sSc[b] + sTR[lt * 16 + END_TAG]);
        }
    }
    __syncthreads();
    if (tid == 0) {
        float s = 0.f;
#pragma unroll
        for (int i = 0; i < NB; ++i) s += sRes[i];
        atomicAdd(out, s);
    }
}

extern "C" void kernel_launch(void* const* d_in, const int* in_sizes, int n_in,
                              void* d_out, int out_size, void* d_ws, size_t ws_size,
                              hipStream_t stream) {
    const float* em = (const float*)d_in[0];
    const int*   tg = (const int*)d_in[1];
    const float* mk = (const float*)d_in[2];
    const float* tr = (const float*)d_in[3];
    float* out = (float*)d_out;

    hipMemsetAsync(out, 0, sizeof(float), stream);
    crf_pipe<<<BS / NB, 1024, 0, stream>>>(em, tg, mk, tr, out);
}